// Round 5
// baseline (418.684 us; speedup 1.0000x reference)
//
#include <hip/hip_runtime.h>
#include <hip/hip_bf16.h>

typedef unsigned short u16;
typedef unsigned int u32;
typedef __attribute__((ext_vector_type(8))) __bf16 bf16x8;
typedef __attribute__((ext_vector_type(4))) float f32x4;
typedef __attribute__((ext_vector_type(16))) float f32x16;

#define LOG2E 1.4426950408889634f

__device__ __forceinline__ u16 f2bf(float f) {
  union { __hip_bfloat16 h; u16 u; } cv;
  cv.h = __float2bfloat16(f);
  return cv.u;
}

__device__ __forceinline__ u32 pk2(float a, float b) {
  return (u32)f2bf(a) | ((u32)f2bf(b) << 16);
}

__device__ __forceinline__ f32x4 mfma16(bf16x8 a, bf16x8 b, f32x4 c) {
  return __builtin_amdgcn_mfma_f32_16x16x32_bf16(a, b, c, 0, 0, 0);
}
__device__ __forceinline__ f32x16 mfma32(bf16x8 a, bf16x8 b, f32x16 c) {
  return __builtin_amdgcn_mfma_f32_32x32x16_bf16(a, b, c, 0, 0, 0);
}

// async global->LDS, 16B per lane, dest = wave-uniform base + lane*16
__device__ __forceinline__ void gload16(const u16* g, u16* lds) {
  __builtin_amdgcn_global_load_lds(
      (const __attribute__((address_space(1))) u32*)g,
      (__attribute__((address_space(3))) u32*)lds, 16, 0, 0);
}

// ---- W[K][N] f32 -> WT[N][K] bf16 (coalesced writes) ----
__global__ void cast_transpose(const float* __restrict__ W, u16* __restrict__ WT,
                               int K, int N) {
  int idx = blockIdx.x * 256 + threadIdx.x;
  if (idx >= K * N) return;
  int n = idx / K, k = idx - n * K;
  WT[idx] = f2bf(W[(size_t)k * N + n]);
}

// ---- LayerNorm over 512, one wave per row, f32 in -> bf16 out ----
__global__ __launch_bounds__(64) void ln_kernel(const float* __restrict__ X,
                                                const float* __restrict__ gam,
                                                const float* __restrict__ bet,
                                                u16* __restrict__ Y) {
  int row = blockIdx.x, l = threadIdx.x;
  const float4* xp = reinterpret_cast<const float4*>(X + (size_t)row * 512);
  float4 a = xp[l], c = xp[l + 64];
  float s  = a.x + a.y + a.z + a.w + c.x + c.y + c.z + c.w;
  float s2 = a.x*a.x + a.y*a.y + a.z*a.z + a.w*a.w
           + c.x*c.x + c.y*c.y + c.z*c.z + c.w*c.w;
#pragma unroll
  for (int m = 1; m < 64; m <<= 1) { s += __shfl_xor(s, m); s2 += __shfl_xor(s2, m); }
  float mu = s * (1.f / 512.f);
  float rs = rsqrtf(s2 * (1.f / 512.f) - mu * mu + 1e-5f);
  const float4* gp = reinterpret_cast<const float4*>(gam);
  const float4* bp = reinterpret_cast<const float4*>(bet);
  float4 g0 = gp[l], g1 = gp[l + 64], b0 = bp[l], b1 = bp[l + 64];
  ushort4 o;
  o.x = f2bf((a.x - mu) * rs * g0.x + b0.x);
  o.y = f2bf((a.y - mu) * rs * g0.y + b0.y);
  o.z = f2bf((a.z - mu) * rs * g0.z + b0.z);
  o.w = f2bf((a.w - mu) * rs * g0.w + b0.w);
  reinterpret_cast<ushort4*>(Y + (size_t)row * 512)[l] = o;
  o.x = f2bf((c.x - mu) * rs * g1.x + b1.x);
  o.y = f2bf((c.y - mu) * rs * g1.y + b1.y);
  o.z = f2bf((c.z - mu) * rs * g1.z + b1.z);
  o.w = f2bf((c.w - mu) * rs * g1.w + b1.w);
  reinterpret_cast<ushort4*>(Y + (size_t)row * 512)[l + 64] = o;
}

// ---- NT GEMM: C[m][n] = sum_k A[m][k] * BT[n][k], bf16 in, fp32 acc ----
// BMxBN=BMx128 tile, BK=32, 256 thr (4 waves, 2x2), global_load_lds staging,
// linear LDS (stride 32 shorts), m97 2-barrier structure.
// EPI: 0=qkv scatter  1=proj+residual->f32  2=gelu->bf16  3=out += acc+bias
template <int EPI, int BM>
__global__ __launch_bounds__(256) void gemm_bt(
    const u16* __restrict__ A, const u16* __restrict__ BT,
    int M, int N, int K,
    const float* __restrict__ bias,
    const float* __restrict__ resid,
    float* __restrict__ outF,
    u16* __restrict__ outU,
    u16* __restrict__ Qo, u16* __restrict__ Ko, u16* __restrict__ VTo) {
  constexpr int MFR = BM / 32;       // M fragments per wave (16-rows each)
  constexpr int CA = BM / 64;        // A chunks (1KB) staged per wave
  __shared__ u16 As[BM * 32];
  __shared__ u16 Bs[128 * 32];
  const int tid = threadIdx.x;
  const int wid = tid >> 6, l = tid & 63;
  const int lg = l >> 4, ll = l & 15;
  const int m0 = blockIdx.y * BM, n0 = blockIdx.x * 128;
  const int wm = (wid >> 1) * (BM / 2), wn = (wid & 1) * 64;
  const f32x4 zf = {0.f, 0.f, 0.f, 0.f};
  f32x4 acc[MFR][4];
#pragma unroll
  for (int i = 0; i < MFR; i++)
#pragma unroll
    for (int j = 0; j < 4; j++) acc[i][j] = zf;

  const int srow = l >> 2, scol = (l & 3) * 8;
  const u16* Ag = A + (size_t)(m0 + wid * CA * 16 + srow) * K + scol;
  const u16* Bg = BT + (size_t)(n0 + wid * 32 + srow) * K + scol;
  u16* lA = As + wid * CA * 512;
  u16* lB = Bs + wid * 1024;

  for (int kt = 0; kt < K; kt += 32) {
    __syncthreads();
#pragma unroll
    for (int c = 0; c < CA; c++)
      gload16(Ag + (size_t)c * 16 * K + kt, lA + c * 512);
    gload16(Bg + kt, lB);
    gload16(Bg + (size_t)16 * K + kt, lB + 512);
    __syncthreads();
    bf16x8 af[MFR], bfr[4];
#pragma unroll
    for (int i = 0; i < MFR; i++)
      af[i] = *reinterpret_cast<const bf16x8*>(As + (wm + i * 16 + ll) * 32 + lg * 8);
#pragma unroll
    for (int j = 0; j < 4; j++)
      bfr[j] = *reinterpret_cast<const bf16x8*>(Bs + (wn + j * 16 + ll) * 32 + lg * 8);
#pragma unroll
    for (int i = 0; i < MFR; i++)
#pragma unroll
      for (int j = 0; j < 4; j++)
        acc[i][j] = mfma16(af[i], bfr[j], acc[i][j]);
  }

#pragma unroll
  for (int i = 0; i < MFR; i++) {
#pragma unroll
    for (int j = 0; j < 4; j++) {
      int col = n0 + wn + j * 16 + ll;
      float bcol = bias[col];
      int rbase = m0 + wm + i * 16 + lg * 4;
#pragma unroll
      for (int r = 0; r < 4; r++) {
        int row = rbase + r;
        float val = acc[i][j][r] + bcol;
        if (EPI == 0) {
          int bi = row >> 11, nseq = row & 2047;
          int t = col >> 9, rem = col & 511;
          int hh = rem >> 6, dd = rem & 63;
          size_t hidx = ((size_t)((bi << 3) + hh) * 2048 + nseq) * 64 + dd;
          // Q pre-scaled by 1/sqrt(64) * log2(e) so attn uses exp2 directly
          if (t == 0)      Qo[hidx] = f2bf(val * (0.125f * LOG2E));
          else if (t == 1) Ko[hidx] = f2bf(val);
          else VTo[((size_t)((bi << 3) + hh) * 64 + dd) * 2048 + nseq] = f2bf(val);
        } else if (EPI == 1) {
          size_t idx = (size_t)row * 512 + col;
          outF[idx] = val + resid[idx];
        } else if (EPI == 2) {
          float gv = 0.5f * val * (1.f + erff(val * 0.70710678f));
          outU[(size_t)row * 2048 + col] = f2bf(gv);
        } else {
          size_t idx = (size_t)row * 512 + col;
          outF[idx] = val + resid[idx];
        }
      }
    }
  }
}

// ---- flash attention, swapped-QK^T in-register softmax, pipelined loads,
// block-level KV-split (kvsplit=2): each block does 1024 kv, writes fp32
// partial O (unnormalized) + (m,l) stats; attn_merge combines.
// Q[B,H,N,D] (pre-scaled by 0.125*log2e), K[B,H,N,D], VT[B,H,D,N], all bf16.
// grid (32, 8, 4): x = qtile*2 + split; 4 waves; wave owns 32 q rows; KVBLK=64.
// S^T = mfma32(K_frag, Q_frag): lane holds col q = l&31, rows k=(r&3)+8*(r>>2)+4*(l>>5).
__device__ __forceinline__ void attn_tile(
    int KB, int KNB, const u16* __restrict__ Kh, const u16* __restrict__ Vh,
    const bf16x8 (&qf)[4], bf16x8 (&KC)[2][4], bf16x8 (&KN)[2][4],
    f32x16 (&oacc)[2], float& m, float& lsum, int lq, int h) {
  // V(t) loads issued first: softmax phase hides their latency
  bf16x8 vreg[2][4];
#pragma unroll
  for (int dt = 0; dt < 2; dt++)
#pragma unroll
    for (int ks = 0; ks < 4; ks++)
      vreg[dt][ks] = *reinterpret_cast<const bf16x8*>(
          Vh + (size_t)(dt * 32 + lq) * 2048 + KB + ks * 16 + h * 8);

  // QK^T from current K regs
  f32x16 st[2];
#pragma unroll
  for (int t = 0; t < 2; t++) {
    f32x16 a;
#pragma unroll
    for (int r = 0; r < 16; r++) a[r] = 0.f;
#pragma unroll
    for (int s = 0; s < 4; s++) a = mfma32(KC[t][s], qf[s], a);
    st[t] = a;
  }

  // prefetch next tile's K
#pragma unroll
  for (int t = 0; t < 2; t++)
#pragma unroll
    for (int s = 0; s < 4; s++)
      KN[t][s] = *reinterpret_cast<const bf16x8*>(
          Kh + (size_t)(KNB + t * 32 + lq) * 64 + s * 16 + h * 8);

  // tile max (tree, depth 4) then combine halves
  float red[16];
#pragma unroll
  for (int j = 0; j < 16; j++) red[j] = fmaxf(st[0][j], st[1][j]);
#pragma unroll
  for (int w = 8; w >= 1; w >>= 1)
#pragma unroll
    for (int j = 0; j < w; j++) red[j] = fmaxf(red[j], red[j + w]);
  float pmax = fmaxf(red[0], __shfl_xor(red[0], 32));

  // defer-max: rescale only when running max grew by > 8 (log2 domain)
  if (!__all(pmax - m <= 8.0f)) {
    float mnew = fmaxf(m, pmax);
    float alpha = exp2f(m - mnew);
    m = mnew;
    lsum *= alpha;
#pragma unroll
    for (int r = 0; r < 16; r++) {
      float ar = __shfl(alpha, (r & 3) + 8 * (r >> 2) + 4 * h);
      oacc[0][r] *= ar;
      oacc[1][r] *= ar;
    }
  }

  // P = exp2(S - m), partial row sums (ILP)
  float s0 = 0.f, s1 = 0.f, s2 = 0.f, s3 = 0.f;
#pragma unroll
  for (int t = 0; t < 2; t++)
#pragma unroll
    for (int j = 0; j < 16; j += 4) {
      float p0 = exp2f(st[t][j + 0] - m);
      float p1 = exp2f(st[t][j + 1] - m);
      float p2 = exp2f(st[t][j + 2] - m);
      float p3 = exp2f(st[t][j + 3] - m);
      st[t][j + 0] = p0; st[t][j + 1] = p1; st[t][j + 2] = p2; st[t][j + 3] = p3;
      s0 += p0; s1 += p1; s2 += p2; s3 += p3;
    }
  float rs = (s0 + s1) + (s2 + s3);
  rs += __shfl_xor(rs, 32);
  lsum += rs;

  // Build PV A-fragments: lane needs P[q=lq][k = ks*16 + h*8 + 0..7];
  // half live at lane^32. permlane32_swap gives both outputs in one op.
  uint4 pa[4];
#pragma unroll
  for (int ks = 0; ks < 4; ks++) {
    const int t = ks >> 1, rlo = (ks & 1) * 8;
    u32 w0 = pk2(st[t][rlo + 0], st[t][rlo + 1]);
    u32 w1 = pk2(st[t][rlo + 2], st[t][rlo + 3]);
    u32 w2 = pk2(st[t][rlo + 4], st[t][rlo + 5]);
    u32 w3 = pk2(st[t][rlo + 6], st[t][rlo + 7]);
#if __has_builtin(__builtin_amdgcn_permlane32_swap)
    auto r02 = __builtin_amdgcn_permlane32_swap(w0, w2, false, false);
    auto r13 = __builtin_amdgcn_permlane32_swap(w1, w3, false, false);
    pa[ks].x = (u32)r02[0];
    pa[ks].y = (u32)r13[0];
    pa[ks].z = (u32)r02[1];
    pa[ks].w = (u32)r13[1];
#else
    u32 ka = h ? w2 : w0, kb2 = h ? w3 : w1;
    u32 sa = h ? w0 : w2, sb = h ? w1 : w3;
    u32 ra = (u32)__shfl_xor((int)sa, 32);
    u32 rb = (u32)__shfl_xor((int)sb, 32);
    pa[ks].x = h ? ra : ka;
    pa[ks].y = h ? rb : kb2;
    pa[ks].z = h ? ka : ra;
    pa[ks].w = h ? kb2 : rb;
#endif
  }

  // PV: O[q][d] += P * V
#pragma unroll
  for (int dt = 0; dt < 2; dt++)
#pragma unroll
    for (int ks = 0; ks < 4; ks++) {
      union { uint4 u; bf16x8 v; } pu;
      pu.u = pa[ks];
      oacc[dt] = mfma32(pu.v, vreg[dt][ks], oacc[dt]);
    }
}

__global__ __launch_bounds__(256, 4) void attn_kernel(const u16* __restrict__ Q,
                                                      const u16* __restrict__ Kt,
                                                      const u16* __restrict__ VT,
                                                      float* __restrict__ Opart,
                                                      float2* __restrict__ Stat) {
  const int tid = threadIdx.x;
  const int wid = tid >> 6, l = tid & 63;
  const int lq = l & 31, h = l >> 5;
  const int b = blockIdx.z, hd = blockIdx.y;
  const int qt = blockIdx.x >> 1, sp = blockIdx.x & 1;
  const int qbase = qt * 128 + wid * 32;
  const int kv0 = sp * 1024;
  const size_t hoff = (size_t)(b * 8 + hd) * 2048 * 64;
  const u16* Qh = Q + hoff;
  const u16* Kh = Kt + hoff;
  const u16* Vh = VT + hoff;   // [D=64][N=2048]

  bf16x8 qf[4];
#pragma unroll
  for (int s = 0; s < 4; s++)
    qf[s] = *reinterpret_cast<const bf16x8*>(Qh + (size_t)(qbase + lq) * 64 + s * 16 + h * 8);

  f32x16 oacc[2];
#pragma unroll
  for (int r = 0; r < 16; r++) { oacc[0][r] = 0.f; oacc[1][r] = 0.f; }
  float m = -INFINITY, lsum = 0.f;

  // named K double-buffers, manual 2x body (no runtime-indexed frag arrays)
  bf16x8 kA[2][4], kB[2][4];
#pragma unroll
  for (int t = 0; t < 2; t++)
#pragma unroll
    for (int s = 0; s < 4; s++)
      kA[t][s] = *reinterpret_cast<const bf16x8*>(
          Kh + (size_t)(kv0 + t * 32 + lq) * 64 + s * 16 + h * 8);

  for (int kb = kv0; kb < kv0 + 1024; kb += 128) {
    int nxt = (kb + 128 == kv0 + 1024) ? kv0 : kb + 128;
    attn_tile(kb,      kb + 64, Kh, Vh, qf, kA, kB, oacc, m, lsum, lq, h);
    attn_tile(kb + 64, nxt,     Kh, Vh, qf, kB, kA, oacc, m, lsum, lq, h);
  }

  // write unnormalized fp32 partial O + per-row stats
  float* Op = Opart + (size_t)sp * 8192 * 512;
#pragma unroll
  for (int r = 0; r < 16; r++) {
    const int qr = (r & 3) + 8 * (r >> 2) + 4 * h;
    size_t row = (size_t)b * 2048 + qbase + qr;
#pragma unroll
    for (int dt = 0; dt < 2; dt++) {
      int col = hd * 64 + dt * 32 + lq;
      Op[row * 512 + col] = oacc[dt][r];
    }
  }
  if (h == 0) {
    float2 st2; st2.x = m; st2.y = lsum;
    Stat[(size_t)sp * 32 * 2048 + (size_t)(b * 8 + hd) * 2048 + qbase + lq] = st2;
  }
}

// combine the two KV-split partials: O = (O0*e0 + O1*e1) / (l0*e0 + l1*e1)
__global__ __launch_bounds__(256) void attn_merge(const float* __restrict__ Opart,
                                                  const float2* __restrict__ Stat,
                                                  u16* __restrict__ O) {
  int gid = blockIdx.x * 256 + threadIdx.x;   // 8192 rows * 64 chunks
  int row = gid >> 6;
  int c8 = (gid & 63) * 8;
  int hd = c8 >> 6;
  int bh = (row >> 11) * 8 + hd;
  int n = row & 2047;
  float2 s0 = Stat[(size_t)bh * 2048 + n];
  float2 s1 = Stat[(size_t)32 * 2048 + (size_t)bh * 2048 + n];
  float mm = fmaxf(s0.x, s1.x);
  float c0 = exp2f(s0.x - mm), c1 = exp2f(s1.x - mm);
  float li = 1.0f / (s0.y * c0 + s1.y * c1);
  c0 *= li; c1 *= li;
  const float4* p0 = reinterpret_cast<const float4*>(Opart + (size_t)row * 512 + c8);
  const float4* p1 = reinterpret_cast<const float4*>(Opart + (size_t)8192 * 512 + (size_t)row * 512 + c8);
  float4 a0 = p0[0], a1 = p0[1];
  float4 b0 = p1[0], b1 = p1[1];
  ushort4 o0, o1;
  o0.x = f2bf(a0.x * c0 + b0.x * c1);
  o0.y = f2bf(a0.y * c0 + b0.y * c1);
  o0.z = f2bf(a0.z * c0 + b0.z * c1);
  o0.w = f2bf(a0.w * c0 + b0.w * c1);
  o1.x = f2bf(a1.x * c0 + b1.x * c1);
  o1.y = f2bf(a1.y * c0 + b1.y * c1);
  o1.z = f2bf(a1.z * c0 + b1.z * c1);
  o1.w = f2bf(a1.w * c0 + b1.w * c1);
  ushort4* op = reinterpret_cast<ushort4*>(O + (size_t)row * 512 + c8);
  op[0] = o0;
  op[1] = o1;
}

extern "C" void kernel_launch(void* const* d_in, const int* in_sizes, int n_in,
                              void* d_out, int out_size, void* d_ws, size_t ws_size,
                              hipStream_t stream) {
  const float* x      = (const float*)d_in[0];
  const float* ln1_g  = (const float*)d_in[1];
  const float* ln1_b  = (const float*)d_in[2];
  const float* w_qkv  = (const float*)d_in[3];
  const float* b_qkv  = (const float*)d_in[4];
  const float* w_proj = (const float*)d_in[5];
  const float* b_proj = (const float*)d_in[6];
  const float* ln2_g  = (const float*)d_in[7];
  const float* ln2_b  = (const float*)d_in[8];
  const float* w1     = (const float*)d_in[9];
  const float* b1     = (const float*)d_in[10];
  const float* w2     = (const float*)d_in[11];
  const float* b2     = (const float*)d_in[12];
  float* out = (float*)d_out;

  const int M = 8192;  // B*N rows
  char* w = (char*)d_ws;
  u16* wqkvT  = (u16*)w; w += (size_t)1536 * 512 * 2;
  u16* wprojT = (u16*)w; w += (size_t)512 * 512 * 2;
  u16* w1T    = (u16*)w; w += (size_t)2048 * 512 * 2;
  u16* w2T    = (u16*)w; w += (size_t)512 * 2048 * 2;
  u16* h1     = (u16*)w; w += (size_t)M * 512 * 2;
  u16* Qb     = (u16*)w; w += (size_t)M * 512 * 2;
  u16* Kb     = (u16*)w; w += (size_t)M * 512 * 2;
  u16* VTb    = (u16*)w; w += (size_t)M * 512 * 2;
  u16* attn   = (u16*)w; w += (size_t)M * 512 * 2;
  u16* h2     = (u16*)w; w += (size_t)M * 512 * 2;
  u16* mid    = (u16*)w; w += (size_t)M * 2048 * 2;   // reused as fp32 attn partials
  float2* Stat = (float2*)w; w += (size_t)2 * 32 * 2048 * sizeof(float2);
  float* Opart = (float*)mid;   // 32 MB, lifetime-disjoint with MLP mid

  cast_transpose<<<(512 * 1536 + 255) / 256, 256, 0, stream>>>(w_qkv, wqkvT, 512, 1536);
  cast_transpose<<<(512 * 512 + 255) / 256, 256, 0, stream>>>(w_proj, wprojT, 512, 512);
  cast_transpose<<<(512 * 2048 + 255) / 256, 256, 0, stream>>>(w1, w1T, 512, 2048);
  cast_transpose<<<(2048 * 512 + 255) / 256, 256, 0, stream>>>(w2, w2T, 2048, 512);

  ln_kernel<<<M, 64, 0, stream>>>(x, ln1_g, ln1_b, h1);

  gemm_bt<0, 128><<<dim3(1536 / 128, M / 128), 256, 0, stream>>>(
      h1, wqkvT, M, 1536, 512, b_qkv, nullptr, nullptr, nullptr, Qb, Kb, VTb);

  attn_kernel<<<dim3(32, 8, 4), 256, 0, stream>>>(Qb, Kb, VTb, Opart, Stat);
  attn_merge<<<M * 64 / 256, 256, 0, stream>>>(Opart, Stat, attn);

  gemm_bt<1, 64><<<dim3(512 / 128, M / 64), 256, 0, stream>>>(
      attn, wprojT, M, 512, 512, b_proj, x, out, nullptr, nullptr, nullptr, nullptr);

  ln_kernel<<<M, 64, 0, stream>>>(out, ln2_g, ln2_b, h2);

  gemm_bt<2, 128><<<dim3(2048 / 128, M / 128), 256, 0, stream>>>(
      h2, w1T, M, 2048, 512, b1, nullptr, nullptr, mid, nullptr, nullptr, nullptr);

  gemm_bt<3, 64><<<dim3(512 / 128, M / 64), 256, 0, stream>>>(
      mid, w2T, M, 512, 2048, b2, out, out, nullptr, nullptr, nullptr, nullptr);
}

// Round 6
// 291.927 us; speedup vs baseline: 1.4342x; 1.4342x over previous
//
#include <hip/hip_runtime.h>
#include <hip/hip_bf16.h>

typedef unsigned short u16;
typedef unsigned int u32;
typedef __attribute__((ext_vector_type(8))) __bf16 bf16x8;
typedef __attribute__((ext_vector_type(4))) float f32x4;
typedef __attribute__((ext_vector_type(16))) float f32x16;

#define LOG2E 1.4426950408889634f

__device__ __forceinline__ u16 f2bf(float f) {
  union { __hip_bfloat16 h; u16 u; } cv;
  cv.h = __float2bfloat16(f);
  return cv.u;
}

__device__ __forceinline__ u32 pk2(float a, float b) {
  return (u32)f2bf(a) | ((u32)f2bf(b) << 16);
}

__device__ __forceinline__ f32x4 mfma16(bf16x8 a, bf16x8 b, f32x4 c) {
  return __builtin_amdgcn_mfma_f32_16x16x32_bf16(a, b, c, 0, 0, 0);
}
__device__ __forceinline__ f32x16 mfma32(bf16x8 a, bf16x8 b, f32x16 c) {
  return __builtin_amdgcn_mfma_f32_32x32x16_bf16(a, b, c, 0, 0, 0);
}

// async global->LDS, 16B per lane, dest = wave-uniform base + lane*16
__device__ __forceinline__ void gload16(const u16* g, u16* lds) {
  __builtin_amdgcn_global_load_lds(
      (const __attribute__((address_space(1))) u32*)g,
      (__attribute__((address_space(3))) u32*)lds, 16, 0, 0);
}

// ---- W[K][N] f32 -> WT[N][K] bf16 (coalesced writes) ----
__global__ void cast_transpose(const float* __restrict__ W, u16* __restrict__ WT,
                               int K, int N) {
  int idx = blockIdx.x * 256 + threadIdx.x;
  if (idx >= K * N) return;
  int n = idx / K, k = idx - n * K;
  WT[idx] = f2bf(W[(size_t)k * N + n]);
}

// ---- LayerNorm over 512, one wave per row, f32 in -> bf16 out ----
__global__ __launch_bounds__(64) void ln_kernel(const float* __restrict__ X,
                                                const float* __restrict__ gam,
                                                const float* __restrict__ bet,
                                                u16* __restrict__ Y) {
  int row = blockIdx.x, l = threadIdx.x;
  const float4* xp = reinterpret_cast<const float4*>(X + (size_t)row * 512);
  float4 a = xp[l], c = xp[l + 64];
  float s  = a.x + a.y + a.z + a.w + c.x + c.y + c.z + c.w;
  float s2 = a.x*a.x + a.y*a.y + a.z*a.z + a.w*a.w
           + c.x*c.x + c.y*c.y + c.z*c.z + c.w*c.w;
#pragma unroll
  for (int m = 1; m < 64; m <<= 1) { s += __shfl_xor(s, m); s2 += __shfl_xor(s2, m); }
  float mu = s * (1.f / 512.f);
  float rs = rsqrtf(s2 * (1.f / 512.f) - mu * mu + 1e-5f);
  const float4* gp = reinterpret_cast<const float4*>(gam);
  const float4* bp = reinterpret_cast<const float4*>(bet);
  float4 g0 = gp[l], g1 = gp[l + 64], b0 = bp[l], b1 = bp[l + 64];
  ushort4 o;
  o.x = f2bf((a.x - mu) * rs * g0.x + b0.x);
  o.y = f2bf((a.y - mu) * rs * g0.y + b0.y);
  o.z = f2bf((a.z - mu) * rs * g0.z + b0.z);
  o.w = f2bf((a.w - mu) * rs * g0.w + b0.w);
  reinterpret_cast<ushort4*>(Y + (size_t)row * 512)[l] = o;
  o.x = f2bf((c.x - mu) * rs * g1.x + b1.x);
  o.y = f2bf((c.y - mu) * rs * g1.y + b1.y);
  o.z = f2bf((c.z - mu) * rs * g1.z + b1.z);
  o.w = f2bf((c.w - mu) * rs * g1.w + b1.w);
  reinterpret_cast<ushort4*>(Y + (size_t)row * 512)[l + 64] = o;
}

// ---- NT GEMM: C[m][n] = sum_k A[m][k] * BT[n][k], bf16 in, fp32 acc ----
// BMxBN=BMx128 tile, BK=32, 256 thr (4 waves, 2x2), global_load_lds staging,
// linear LDS (stride 32 shorts), m97 2-barrier structure.
// EPI: 0=qkv scatter  1=proj+residual->f32  2=gelu->bf16  3=out += acc+bias
template <int EPI, int BM>
__global__ __launch_bounds__(256) void gemm_bt(
    const u16* __restrict__ A, const u16* __restrict__ BT,
    int M, int N, int K,
    const float* __restrict__ bias,
    const float* __restrict__ resid,
    float* __restrict__ outF,
    u16* __restrict__ outU,
    u16* __restrict__ Qo, u16* __restrict__ Ko, u16* __restrict__ VTo) {
  constexpr int MFR = BM / 32;       // M fragments per wave (16-rows each)
  constexpr int CA = BM / 64;        // A chunks (1KB) staged per wave
  __shared__ u16 As[BM * 32];
  __shared__ u16 Bs[128 * 32];
  const int tid = threadIdx.x;
  const int wid = tid >> 6, l = tid & 63;
  const int lg = l >> 4, ll = l & 15;
  const int m0 = blockIdx.y * BM, n0 = blockIdx.x * 128;
  const int wm = (wid >> 1) * (BM / 2), wn = (wid & 1) * 64;
  const f32x4 zf = {0.f, 0.f, 0.f, 0.f};
  f32x4 acc[MFR][4];
#pragma unroll
  for (int i = 0; i < MFR; i++)
#pragma unroll
    for (int j = 0; j < 4; j++) acc[i][j] = zf;

  const int srow = l >> 2, scol = (l & 3) * 8;
  const u16* Ag = A + (size_t)(m0 + wid * CA * 16 + srow) * K + scol;
  const u16* Bg = BT + (size_t)(n0 + wid * 32 + srow) * K + scol;
  u16* lA = As + wid * CA * 512;
  u16* lB = Bs + wid * 1024;

  for (int kt = 0; kt < K; kt += 32) {
    __syncthreads();
#pragma unroll
    for (int c = 0; c < CA; c++)
      gload16(Ag + (size_t)c * 16 * K + kt, lA + c * 512);
    gload16(Bg + kt, lB);
    gload16(Bg + (size_t)16 * K + kt, lB + 512);
    __syncthreads();
    bf16x8 af[MFR], bfr[4];
#pragma unroll
    for (int i = 0; i < MFR; i++)
      af[i] = *reinterpret_cast<const bf16x8*>(As + (wm + i * 16 + ll) * 32 + lg * 8);
#pragma unroll
    for (int j = 0; j < 4; j++)
      bfr[j] = *reinterpret_cast<const bf16x8*>(Bs + (wn + j * 16 + ll) * 32 + lg * 8);
#pragma unroll
    for (int i = 0; i < MFR; i++)
#pragma unroll
      for (int j = 0; j < 4; j++)
        acc[i][j] = mfma16(af[i], bfr[j], acc[i][j]);
  }

#pragma unroll
  for (int i = 0; i < MFR; i++) {
#pragma unroll
    for (int j = 0; j < 4; j++) {
      int col = n0 + wn + j * 16 + ll;
      float bcol = bias[col];
      int rbase = m0 + wm + i * 16 + lg * 4;
#pragma unroll
      for (int r = 0; r < 4; r++) {
        int row = rbase + r;
        float val = acc[i][j][r] + bcol;
        if (EPI == 0) {
          int bi = row >> 11, nseq = row & 2047;
          int t = col >> 9, rem = col & 511;
          int hh = rem >> 6, dd = rem & 63;
          size_t hidx = ((size_t)((bi << 3) + hh) * 2048 + nseq) * 64 + dd;
          // Q pre-scaled by 1/sqrt(64) * log2(e) so attn uses exp2 directly
          if (t == 0)      Qo[hidx] = f2bf(val * (0.125f * LOG2E));
          else if (t == 1) Ko[hidx] = f2bf(val);
          else VTo[((size_t)((bi << 3) + hh) * 64 + dd) * 2048 + nseq] = f2bf(val);
        } else if (EPI == 1) {
          size_t idx = (size_t)row * 512 + col;
          outF[idx] = val + resid[idx];
        } else if (EPI == 2) {
          float gv = 0.5f * val * (1.f + erff(val * 0.70710678f));
          outU[(size_t)row * 2048 + col] = f2bf(gv);
        } else {
          size_t idx = (size_t)row * 512 + col;
          outF[idx] = val + resid[idx];
        }
      }
    }
  }
}

// ---- flash attention, swapped-QK^T in-register softmax, pipelined loads,
// block-level KV-split (kvsplit=2): each block does 1024 kv, writes fp32
// partial O (unnormalized) + (m,l) stats; attn_merge combines.
// Q[B,H,N,D] (pre-scaled by 0.125*log2e), K[B,H,N,D], VT[B,H,D,N], all bf16.
// grid (32, 8, 4): x = qtile*2 + split; 4 waves; wave owns 32 q rows; KVBLK=64.
// S^T = mfma32(K_frag, Q_frag): lane holds col q = l&31, rows k=(r&3)+8*(r>>2)+4*(l>>5).
__device__ __forceinline__ void attn_tile(
    int KB, int KNB, const u16* __restrict__ Kh, const u16* __restrict__ Vh,
    const bf16x8 (&qf)[4], bf16x8 (&KC)[2][4], bf16x8 (&KN)[2][4],
    f32x16 (&oacc)[2], float& m, float& lsum, int lq, int h) {
  // V(t) loads issued first: softmax phase hides their latency
  bf16x8 vreg[2][4];
#pragma unroll
  for (int dt = 0; dt < 2; dt++)
#pragma unroll
    for (int ks = 0; ks < 4; ks++)
      vreg[dt][ks] = *reinterpret_cast<const bf16x8*>(
          Vh + (size_t)(dt * 32 + lq) * 2048 + KB + ks * 16 + h * 8);

  // QK^T from current K regs
  f32x16 st[2];
#pragma unroll
  for (int t = 0; t < 2; t++) {
    f32x16 a;
#pragma unroll
    for (int r = 0; r < 16; r++) a[r] = 0.f;
#pragma unroll
    for (int s = 0; s < 4; s++) a = mfma32(KC[t][s], qf[s], a);
    st[t] = a;
  }

  // prefetch next tile's K
#pragma unroll
  for (int t = 0; t < 2; t++)
#pragma unroll
    for (int s = 0; s < 4; s++)
      KN[t][s] = *reinterpret_cast<const bf16x8*>(
          Kh + (size_t)(KNB + t * 32 + lq) * 64 + s * 16 + h * 8);

  // tile max (tree, depth 4) then combine halves
  float red[16];
#pragma unroll
  for (int j = 0; j < 16; j++) red[j] = fmaxf(st[0][j], st[1][j]);
#pragma unroll
  for (int w = 8; w >= 1; w >>= 1)
#pragma unroll
    for (int j = 0; j < w; j++) red[j] = fmaxf(red[j], red[j + w]);
  float pmax = fmaxf(red[0], __shfl_xor(red[0], 32));

  // defer-max: rescale only when running max grew by > 8 (log2 domain)
  if (!__all(pmax - m <= 8.0f)) {
    float mnew = fmaxf(m, pmax);
    float alpha = exp2f(m - mnew);
    m = mnew;
    lsum *= alpha;
#pragma unroll
    for (int r = 0; r < 16; r++) {
      float ar = __shfl(alpha, (r & 3) + 8 * (r >> 2) + 4 * h);
      oacc[0][r] *= ar;
      oacc[1][r] *= ar;
    }
  }

  // P = exp2(S - m), partial row sums (ILP)
  float s0 = 0.f, s1 = 0.f, s2 = 0.f, s3 = 0.f;
#pragma unroll
  for (int t = 0; t < 2; t++)
#pragma unroll
    for (int j = 0; j < 16; j += 4) {
      float p0 = exp2f(st[t][j + 0] - m);
      float p1 = exp2f(st[t][j + 1] - m);
      float p2 = exp2f(st[t][j + 2] - m);
      float p3 = exp2f(st[t][j + 3] - m);
      st[t][j + 0] = p0; st[t][j + 1] = p1; st[t][j + 2] = p2; st[t][j + 3] = p3;
      s0 += p0; s1 += p1; s2 += p2; s3 += p3;
    }
  float rs = (s0 + s1) + (s2 + s3);
  rs += __shfl_xor(rs, 32);
  lsum += rs;

  // Build PV A-fragments: lane needs P[q=lq][k = ks*16 + h*8 + 0..7];
  // half live at lane^32. permlane32_swap gives both outputs in one op.
  uint4 pa[4];
#pragma unroll
  for (int ks = 0; ks < 4; ks++) {
    const int t = ks >> 1, rlo = (ks & 1) * 8;
    u32 w0 = pk2(st[t][rlo + 0], st[t][rlo + 1]);
    u32 w1 = pk2(st[t][rlo + 2], st[t][rlo + 3]);
    u32 w2 = pk2(st[t][rlo + 4], st[t][rlo + 5]);
    u32 w3 = pk2(st[t][rlo + 6], st[t][rlo + 7]);
#if __has_builtin(__builtin_amdgcn_permlane32_swap)
    auto r02 = __builtin_amdgcn_permlane32_swap(w0, w2, false, false);
    auto r13 = __builtin_amdgcn_permlane32_swap(w1, w3, false, false);
    pa[ks].x = (u32)r02[0];
    pa[ks].y = (u32)r13[0];
    pa[ks].z = (u32)r02[1];
    pa[ks].w = (u32)r13[1];
#else
    u32 ka = h ? w2 : w0, kb2 = h ? w3 : w1;
    u32 sa = h ? w0 : w2, sb = h ? w1 : w3;
    u32 ra = (u32)__shfl_xor((int)sa, 32);
    u32 rb = (u32)__shfl_xor((int)sb, 32);
    pa[ks].x = h ? ra : ka;
    pa[ks].y = h ? rb : kb2;
    pa[ks].z = h ? ka : ra;
    pa[ks].w = h ? kb2 : rb;
#endif
  }

  // PV: O[q][d] += P * V
#pragma unroll
  for (int dt = 0; dt < 2; dt++)
#pragma unroll
    for (int ks = 0; ks < 4; ks++) {
      union { uint4 u; bf16x8 v; } pu;
      pu.u = pa[ks];
      oacc[dt] = mfma32(pu.v, vreg[dt][ks], oacc[dt]);
    }
}

__global__ __launch_bounds__(256, 2) void attn_kernel(const u16* __restrict__ Q,
                                                      const u16* __restrict__ Kt,
                                                      const u16* __restrict__ VT,
                                                      float* __restrict__ Opart,
                                                      float2* __restrict__ Stat) {
  const int tid = threadIdx.x;
  const int wid = tid >> 6, l = tid & 63;
  const int lq = l & 31, h = l >> 5;
  const int b = blockIdx.z, hd = blockIdx.y;
  const int qt = blockIdx.x >> 1, sp = blockIdx.x & 1;
  const int qbase = qt * 128 + wid * 32;
  const int kv0 = sp * 1024;
  const size_t hoff = (size_t)(b * 8 + hd) * 2048 * 64;
  const u16* Qh = Q + hoff;
  const u16* Kh = Kt + hoff;
  const u16* Vh = VT + hoff;   // [D=64][N=2048]

  bf16x8 qf[4];
#pragma unroll
  for (int s = 0; s < 4; s++)
    qf[s] = *reinterpret_cast<const bf16x8*>(Qh + (size_t)(qbase + lq) * 64 + s * 16 + h * 8);

  f32x16 oacc[2];
#pragma unroll
  for (int r = 0; r < 16; r++) { oacc[0][r] = 0.f; oacc[1][r] = 0.f; }
  float m = -INFINITY, lsum = 0.f;

  // named K double-buffers, manual 2x body (no runtime-indexed frag arrays)
  bf16x8 kA[2][4], kB[2][4];
#pragma unroll
  for (int t = 0; t < 2; t++)
#pragma unroll
    for (int s = 0; s < 4; s++)
      kA[t][s] = *reinterpret_cast<const bf16x8*>(
          Kh + (size_t)(kv0 + t * 32 + lq) * 64 + s * 16 + h * 8);

  for (int kb = kv0; kb < kv0 + 1024; kb += 128) {
    int nxt = (kb + 128 == kv0 + 1024) ? kv0 : kb + 128;
    attn_tile(kb,      kb + 64, Kh, Vh, qf, kA, kB, oacc, m, lsum, lq, h);
    attn_tile(kb + 64, nxt,     Kh, Vh, qf, kB, kA, oacc, m, lsum, lq, h);
  }

  // write unnormalized fp32 partial O + per-row stats
  float* Op = Opart + (size_t)sp * 8192 * 512;
#pragma unroll
  for (int r = 0; r < 16; r++) {
    const int qr = (r & 3) + 8 * (r >> 2) + 4 * h;
    size_t row = (size_t)b * 2048 + qbase + qr;
#pragma unroll
    for (int dt = 0; dt < 2; dt++) {
      int col = hd * 64 + dt * 32 + lq;
      Op[row * 512 + col] = oacc[dt][r];
    }
  }
  if (h == 0) {
    float2 st2; st2.x = m; st2.y = lsum;
    Stat[(size_t)sp * 32 * 2048 + (size_t)(b * 8 + hd) * 2048 + qbase + lq] = st2;
  }
}

// combine the two KV-split partials: O = (O0*e0 + O1*e1) / (l0*e0 + l1*e1)
__global__ __launch_bounds__(256) void attn_merge(const float* __restrict__ Opart,
                                                  const float2* __restrict__ Stat,
                                                  u16* __restrict__ O) {
  int gid = blockIdx.x * 256 + threadIdx.x;   // 8192 rows * 64 chunks
  int row = gid >> 6;
  int c8 = (gid & 63) * 8;
  int hd = c8 >> 6;
  int bh = (row >> 11) * 8 + hd;
  int n = row & 2047;
  float2 s0 = Stat[(size_t)bh * 2048 + n];
  float2 s1 = Stat[(size_t)32 * 2048 + (size_t)bh * 2048 + n];
  float mm = fmaxf(s0.x, s1.x);
  float c0 = exp2f(s0.x - mm), c1 = exp2f(s1.x - mm);
  float li = 1.0f / (s0.y * c0 + s1.y * c1);
  c0 *= li; c1 *= li;
  const float4* p0 = reinterpret_cast<const float4*>(Opart + (size_t)row * 512 + c8);
  const float4* p1 = reinterpret_cast<const float4*>(Opart + (size_t)8192 * 512 + (size_t)row * 512 + c8);
  float4 a0 = p0[0], a1 = p0[1];
  float4 b0 = p1[0], b1 = p1[1];
  ushort4 o0, o1;
  o0.x = f2bf(a0.x * c0 + b0.x * c1);
  o0.y = f2bf(a0.y * c0 + b0.y * c1);
  o0.z = f2bf(a0.z * c0 + b0.z * c1);
  o0.w = f2bf(a0.w * c0 + b0.w * c1);
  o1.x = f2bf(a1.x * c0 + b1.x * c1);
  o1.y = f2bf(a1.y * c0 + b1.y * c1);
  o1.z = f2bf(a1.z * c0 + b1.z * c1);
  o1.w = f2bf(a1.w * c0 + b1.w * c1);
  ushort4* op = reinterpret_cast<ushort4*>(O + (size_t)row * 512 + c8);
  op[0] = o0;
  op[1] = o1;
}

extern "C" void kernel_launch(void* const* d_in, const int* in_sizes, int n_in,
                              void* d_out, int out_size, void* d_ws, size_t ws_size,
                              hipStream_t stream) {
  const float* x      = (const float*)d_in[0];
  const float* ln1_g  = (const float*)d_in[1];
  const float* ln1_b  = (const float*)d_in[2];
  const float* w_qkv  = (const float*)d_in[3];
  const float* b_qkv  = (const float*)d_in[4];
  const float* w_proj = (const float*)d_in[5];
  const float* b_proj = (const float*)d_in[6];
  const float* ln2_g  = (const float*)d_in[7];
  const float* ln2_b  = (const float*)d_in[8];
  const float* w1     = (const float*)d_in[9];
  const float* b1     = (const float*)d_in[10];
  const float* w2     = (const float*)d_in[11];
  const float* b2     = (const float*)d_in[12];
  float* out = (float*)d_out;

  const int M = 8192;  // B*N rows
  char* w = (char*)d_ws;
  u16* wqkvT  = (u16*)w; w += (size_t)1536 * 512 * 2;
  u16* wprojT = (u16*)w; w += (size_t)512 * 512 * 2;
  u16* w1T    = (u16*)w; w += (size_t)2048 * 512 * 2;
  u16* w2T    = (u16*)w; w += (size_t)512 * 2048 * 2;
  u16* h1     = (u16*)w; w += (size_t)M * 512 * 2;
  u16* Qb     = (u16*)w; w += (size_t)M * 512 * 2;
  u16* Kb     = (u16*)w; w += (size_t)M * 512 * 2;
  u16* VTb    = (u16*)w; w += (size_t)M * 512 * 2;
  u16* attn   = (u16*)w; w += (size_t)M * 512 * 2;
  u16* h2     = (u16*)w; w += (size_t)M * 512 * 2;
  u16* mid    = (u16*)w; w += (size_t)M * 2048 * 2;   // reused as fp32 attn partials
  float2* Stat = (float2*)w; w += (size_t)2 * 32 * 2048 * sizeof(float2);
  float* Opart = (float*)mid;   // 32 MB, lifetime-disjoint with MLP mid

  cast_transpose<<<(512 * 1536 + 255) / 256, 256, 0, stream>>>(w_qkv, wqkvT, 512, 1536);
  cast_transpose<<<(512 * 512 + 255) / 256, 256, 0, stream>>>(w_proj, wprojT, 512, 512);
  cast_transpose<<<(512 * 2048 + 255) / 256, 256, 0, stream>>>(w1, w1T, 512, 2048);
  cast_transpose<<<(2048 * 512 + 255) / 256, 256, 0, stream>>>(w2, w2T, 2048, 512);

  ln_kernel<<<M, 64, 0, stream>>>(x, ln1_g, ln1_b, h1);

  gemm_bt<0, 128><<<dim3(1536 / 128, M / 128), 256, 0, stream>>>(
      h1, wqkvT, M, 1536, 512, b_qkv, nullptr, nullptr, nullptr, Qb, Kb, VTb);

  attn_kernel<<<dim3(32, 8, 4), 256, 0, stream>>>(Qb, Kb, VTb, Opart, Stat);
  attn_merge<<<M * 64 / 256, 256, 0, stream>>>(Opart, Stat, attn);

  gemm_bt<1, 64><<<dim3(512 / 128, M / 64), 256, 0, stream>>>(
      attn, wprojT, M, 512, 512, b_proj, x, out, nullptr, nullptr, nullptr, nullptr);

  ln_kernel<<<M, 64, 0, stream>>>(out, ln2_g, ln2_b, h2);

  gemm_bt<2, 128><<<dim3(2048 / 128, M / 128), 256, 0, stream>>>(
      h2, w1T, M, 2048, 512, b1, nullptr, nullptr, mid, nullptr, nullptr, nullptr);

  gemm_bt<3, 64><<<dim3(512 / 128, M / 64), 256, 0, stream>>>(
      mid, w2T, M, 512, 2048, b2, out, out, nullptr, nullptr, nullptr, nullptr);
}